// Round 6
// baseline (705.098 us; speedup 1.0000x reference)
//
#include <hip/hip_runtime.h>
#include <math.h>

typedef unsigned short u16;
typedef unsigned int u32;
typedef __bf16 bf8_t __attribute__((ext_vector_type(8)));
typedef float f4_t __attribute__((ext_vector_type(4)));
typedef u16 us8_t __attribute__((ext_vector_type(8)));
typedef u16 us4_t __attribute__((ext_vector_type(4)));

#define LDC 224          // padded feature stride (200 -> 224)
#define NROWS 6016       // padded node rows (6000 -> 6016)
#define PLANE (NROWS*LDC)

__device__ __forceinline__ float b2f(u16 x){
  union{u32 u; float f;} c; c.u = ((u32)x)<<16; return c.f;
}
__device__ __forceinline__ u16 f2b(float f){
  union{u32 u; float f;} c; c.f = f;
  u32 b = c.u;
  return (u16)((b + 0x7FFFu + ((b>>16)&1u)) >> 16);
}
__device__ __forceinline__ u16 ldcvt(const void* p, size_t i, int f){
  return f ? f2b(((const float*)p)[i]) : ((const u16*)p)[i];
}
// async global->LDS 16B (wave-uniform base + lane*16 on the LDS side)
__device__ __forceinline__ void gl16(const u16* g, u16* l){
  __builtin_amdgcn_global_load_lds((const __attribute__((address_space(1))) void*)g,
                                   (__attribute__((address_space(3))) void*)l, 16, 0, 0);
}

// -------- one-shot dtype detect -> flag (scalar-loadable by every other kernel) ------
// bf16 values have sign=0, exp in [0x30,0x72]; fp32 low-halves are mantissa noise.
__global__ void detect_kernel(const u16* __restrict__ adj, int* __restrict__ flag)
{
  int l = threadIdx.x;           // 64 threads
  u16 u = adj[2*l];
  int ex = (u >> 7) & 0xFF;
  bool ok = ((u >> 15) == 0) && (ex >= 0x30) && (ex <= 0x72);
  unsigned long long m = __ballot(ok);
  if (l == 0) flag[0] = (__popcll(m) < 32) ? 1 : 0;   // 1 = fp32 inputs
}

// -------- prep: flat 1-D grid, exact compile-time segments ---------------------------
// [0,5320)       weight transposes (coalesced READ, strided write)
// [5320,5333)    misc (spk idx, spk_emb, biases)
// [5333,5347)    x pad rows
// [5347,7907)    a_p  [2048][320]
// [7907,10979)   v_p  [2048][384]
// [10979,15397)  adj -> padded bf16 (cfg==2 only; 4 chunks/thread, batched-load ILP)
#define PB_MISC 5320
#define PB_XPAD 5333
#define PB_AP   5347
#define PB_VP   7907
#define PB_CONV 10979
__global__ void prep_kernel(const int* __restrict__ flag,
                            const void* __restrict__ adj, u16* __restrict__ adj_bf,
                            const void* __restrict__ Wa, const void* __restrict__ Wv,
                            const void* __restrict__ Wl, const void* __restrict__ W0,
                            const void* __restrict__ convW, const void* __restrict__ qmask,
                            const void* __restrict__ a_in, const void* __restrict__ v_in,
                            const void* __restrict__ spkemb_in,
                            const void* __restrict__ ba, const void* __restrict__ bv,
                            const void* __restrict__ bl, const void* __restrict__ b0,
                            u16* __restrict__ WaT, u16* __restrict__ WvT, u16* __restrict__ WlT,
                            u16* __restrict__ W0T, u16* __restrict__ WtT, u16* __restrict__ WbT,
                            int* __restrict__ spk, u16* __restrict__ x_bf,
                            u16* __restrict__ a_p, u16* __restrict__ v_p,
                            u16* __restrict__ spkem, u16* __restrict__ b_all)
{
  const int f = flag[0];
  const int bid = blockIdx.x;
  const int tid = threadIdx.x;

  if (bid < PB_MISC){  // weight transposes; e iterates k-major so reads coalesce
    u32 e = (u32)bid*256u + (u32)tid;     // < 1,361,920 exactly
    const void* src; u16* dst; u32 K, kpad; u32 soff = 0;
    if (e < 71680u){ src=Wa; dst=WaT; K=300; kpad=320; }
    else if (e < 157696u){ e -= 71680u;  src=Wv; dst=WvT; K=342; kpad=384; }
    else if (e < 387072u){ e -= 157696u; src=Wl; dst=WlT; K=1024; kpad=1024; }
    else if (e < 444416u){ e -= 387072u; src=W0; dst=W0T; K=200; kpad=256; }
    else if (e < 903168u){ e -= 444416u; u32 i = e/57344u; e -= i*57344u;
                           src=convW; soff=i*80000u;          dst=WtT + i*57344; K=200; kpad=256; }
    else {                 e -= 903168u; u32 i = e/57344u; e -= i*57344u;
                           src=convW; soff=i*80000u + 40000u; dst=WbT + i*57344; K=200; kpad=256; }
    u32 k = e / 224u, n = e - k*224u;
    u16 val = 0;
    if (k < K && n < 200u) val = ldcvt(src, (size_t)soff + (size_t)k*200u + n, f);
    dst[(size_t)n*kpad + k] = val;
    return;
  }
  if (bid < PB_XPAD){ // misc small stuff
    int e = (bid - PB_MISC)*256 + tid;
    if (e < 2000){
      int b = e/100, t = e - b*100;
      size_t base = ((size_t)t*20 + b)*2;
      bool one;
      if (f) one = ((const float*)qmask)[base+1] > ((const float*)qmask)[base];
      else   one = b2f(((const u16*)qmask)[base+1]) > b2f(((const u16*)qmask)[base]);
      spk[e] = one ? 1 : 0;
    } else if (e < 2400){
      spkem[e-2000] = ldcvt(spkemb_in, e-2000, f);
    } else if (e < 3200){
      int j = e - 2400; int which = j/200, idx = j - which*200;
      const void* src = (which==0)?ba:(which==1)?bv:(which==2)?bl:b0;
      b_all[j] = ldcvt(src, idx, f);
    }
    return;
  }
  if (bid < PB_AP){ // zero pad rows of x
    int e = (bid - PB_XPAD)*256 + tid;
    if (e < 16*LDC) x_bf[(size_t)6000*LDC + e] = 0;
    return;
  }
  if (bid < PB_VP){ // a_p: [2048][320], per element, coalesced
    u32 e = (u32)(bid - PB_AP)*256u + (u32)tid;   // < 655,360 exactly
    u32 row = e / 320u, k = e - row*320u;
    a_p[e] = (row < 2000u && k < 300u) ? ldcvt(a_in, (size_t)row*300u + k, f) : (u16)0;
    return;
  }
  if (bid < PB_CONV){ // v_p: [2048][384]
    u32 e = (u32)(bid - PB_VP)*256u + (u32)tid;   // < 786,432 exactly
    u32 row = e / 384u, k = e - row*384u;
    v_p[e] = (row < 2000u && k < 342u) ? ldcvt(v_in, (size_t)row*342u + k, f) : (u16)0;
    return;
  }
  { // adj -> padded bf16 [6016][6016]; 4 chunks/thread, loads batched for ILP
    if (!adj_bf) return;
    u32 t0 = (u32)(bid - PB_CONV)*256u + (u32)tid;  // < 1,131,008
    u32 rowv[4]; int k8v[4]; int kind[4];           // 0=full,1=tail,2=zero
    f4_t xa[4], xb[4]; us8_t ua[4];
    #pragma unroll
    for (int it=0; it<4; ++it){
      u32 idx = t0 + (u32)it*1131008u;              // < 4,524,032 = 6016*752 exactly
      u32 row = idx / 752u;
      int k8  = (int)(idx - row*752u) * 8;
      rowv[it] = row; k8v[it] = k8;
      if (row < 6000u){
        if (k8 + 8 <= 6000){
          kind[it] = 0;
          if (f){
            const float* src = (const float*)adj + (size_t)row*6000 + k8;
            xa[it] = *(const f4_t*)(src);
            xb[it] = *(const f4_t*)(src + 4);
          } else {
            ua[it] = *(const us8_t*)((const u16*)adj + (size_t)row*6000 + k8);
          }
        } else kind[it] = 1;
      } else kind[it] = 2;
    }
    #pragma unroll
    for (int it=0; it<4; ++it){
      us8_t vv;
      if (kind[it] == 0){
        if (f){
          #pragma unroll
          for (int j=0;j<4;j++){ vv[j] = f2b(xa[it][j]); vv[4+j] = f2b(xb[it][j]); }
        } else vv = ua[it];
      } else if (kind[it] == 1){
        int k8 = k8v[it];
        #pragma unroll
        for (int j=0;j<8;j++){
          int k = k8 + j;
          vv[j] = (k < 6000) ? ldcvt(adj, (size_t)rowv[it]*6000 + k, f) : (u16)0;
        }
      } else {
        #pragma unroll
        for (int j=0;j<8;j++) vv[j] = 0;
      }
      *(us8_t*)(adj_bf + (size_t)rowv[it]*6016 + k8v[it]) = vv;
    }
  }
}

// -------- generic MFMA GEMM, BM=WR*32, BN=224, BK=64, 256 thr -----------------------
// Fast path: double-buffered LDS + counted s_waitcnt vmcnt(N) across raw s_barrier.
// Fallback (fp32 A / tail rows): single-buffer full-drain path.
// dynA: 0 = static bf16 A1
//       1 = dtype-dynamic A1 (flag; fp32 -> VALU-convert staging)
// emode: 0 = bf16 partial plane; 1 = proj(+bias/spk); 2 = h0 relu -> outN + outT
template<int WR>
__global__ __launch_bounds__(256, 2)
void gemm_kernel(int dynA, const int* __restrict__ flag, const u16* __restrict__ a_sel,
                 const void* __restrict__ A1, int lda1, int kv1, int kg1, int ks1, const u16* __restrict__ B1, int ldb1,
                 int Mv, int Mout, int spp, int emode,
                 const u16* __restrict__ bias, const u16* __restrict__ spk_e, const int* __restrict__ spk_idx,
                 u16* __restrict__ part_base,
                 u16* __restrict__ outN, u16* __restrict__ outT)
{
  __shared__ u16 ldsA[2][WR*32*64];
  __shared__ u16 ldsB[2][224*64];
  const int tid = threadIdx.x;
  const int l = tid & 63;
  const int w = tid >> 6;
  const int wrow = w >> 1, wcol = w & 1;
  const int row0 = blockIdx.x * (WR*32);
  const int lq = l >> 4, lr = l & 15;

  const u16* A16 = (const u16*)A1;
  const float* A32 = (const float*)A1;
  int af32 = 0, lda = lda1, kv = kv1, kg = kg1, Mvl = Mv;
  if (dynA){
    int fd = flag[0];
    af32 = fd;
  }

  f4_t acc[WR][7];
  #pragma unroll
  for (int i=0;i<WR;i++)
    #pragma unroll
    for (int j=0;j<7;j++){ f4_t z = {0.f,0.f,0.f,0.f}; acc[i][j] = z; }

  int sb = blockIdx.y * spp, se = sb + spp;
  if (se > ks1) se = ks1;

  auto stageA = [&](int p, int k0){
    const u16* abase = A16 + k0;
    #pragma unroll
    for (int i=0;i<WR;i++){
      int c = (i<<8) + tid;
      int m = c >> 3, k8p = c & 7;
      int k8 = k8p ^ (m & 7);
      gl16(abase + (size_t)(row0+m)*lda + (k8<<3), &ldsA[p][c<<3]);
    }
  };
  auto stageB = [&](int p, int k0){
    const u16* bbase = B1 + k0;
    #pragma unroll
    for (int i=0;i<7;i++){
      int c = (i<<8) + tid;
      int n = c >> 3, k8p = c & 7;
      int k8 = k8p ^ (n & 7);
      gl16(bbase + (size_t)n*ldb1 + (k8<<3), &ldsB[p][c<<3]);
    }
  };
  auto computeT = [&](int p){
    #pragma unroll
    for (int h=0; h<2; ++h){
      bf8_t af[WR], bfr[7];
      int kc = lq + (h<<2);
      #pragma unroll
      for (int rt=0;rt<WR;rt++){
        int m = wrow*(16*WR) + rt*16 + lr;
        af[rt] = *(const bf8_t*)(&ldsA[p][(m<<6) + ((kc ^ (m&7))<<3)]);
      }
      #pragma unroll
      for (int ct=0;ct<7;ct++){
        int n = wcol*112 + ct*16 + lr;
        bfr[ct] = *(const bf8_t*)(&ldsB[p][(n<<6) + ((kc ^ (n&7))<<3)]);
      }
      #pragma unroll
      for (int rt=0;rt<WR;rt++)
        #pragma unroll
        for (int ct=0;ct<7;ct++)
          acc[rt][ct] = __builtin_amdgcn_mfma_f32_16x16x32_bf16(af[rt], bfr[ct], acc[rt][ct], 0,0,0);
    }
  };

  bool pipe = (!af32) && ((lda & 7) == 0) && (row0 + WR*32 <= Mvl)
              && (se > sb) && (se*64 <= kg);

  if (pipe){
    stageA(0, sb<<6); stageB(0, sb<<6);
    int p = 0;
    #pragma unroll 1
    for (int s = sb; s < se; ++s){
      if (s + 1 < se){
        stageA(p^1, (s+1)<<6); stageB(p^1, (s+1)<<6);
        if (WR == 2) asm volatile("s_waitcnt vmcnt(9)" ::: "memory");
        else         asm volatile("s_waitcnt vmcnt(8)" ::: "memory");
      } else {
        asm volatile("s_waitcnt vmcnt(0)" ::: "memory");
      }
      __builtin_amdgcn_s_barrier();   // all waves' buf[p] loads landed
      computeT(p);
      __builtin_amdgcn_s_barrier();   // all waves done reading buf[p]
      p ^= 1;
    }
  } else {
    #pragma unroll 1
    for (int s = sb; s < se; ++s){
      int k0 = s << 6;
      __syncthreads();
      bool alignedA = ((lda & 7) == 0) && (row0 + WR*32 <= Mvl);
      bool gldsA = (!af32) && alignedA && (k0 + 64 <= kg);
      if (gldsA){
        stageA(0, k0);
      } else if (af32 && alignedA && (k0 + 64 <= kv)){
        const float* ap = A32 + (size_t)row0*lda + k0;
        #pragma unroll
        for (int i=0;i<WR;i++){
          int c = (i<<8) + tid;
          int m = c >> 3, k8 = c & 7;
          f4_t x0 = *(const f4_t*)(ap + (size_t)m*lda + (k8<<3));
          f4_t x1 = *(const f4_t*)(ap + (size_t)m*lda + (k8<<3) + 4);
          us8_t vv;
          #pragma unroll
          for (int j=0;j<4;j++){ vv[j] = f2b(x0[j]); vv[4+j] = f2b(x1[j]); }
          *(us8_t*)(&ldsA[0][(m<<6) + ((k8 ^ (m&7))<<3)]) = vv;
        }
      } else {
        #pragma unroll
        for (int i=0;i<WR;i++){
          int c = (i<<8) + tid;
          int m = c >> 3, k8 = c & 7;
          int gr = row0 + m; if (gr > Mvl-1) gr = Mvl-1;
          us8_t vv;
          #pragma unroll
          for (int j=0;j<8;j++){
            int kk = k0 + (k8<<3) + j;
            u16 t = 0;
            if (kk < kv){
              if (af32) t = f2b(A32[(size_t)gr*lda + kk]);
              else      t = A16[(size_t)gr*lda + kk];
            }
            vv[j] = t;
          }
          *(us8_t*)(&ldsA[0][(m<<6) + ((k8 ^ (m&7))<<3)]) = vv;
        }
      }
      stageB(0, k0);
      __syncthreads();
      computeT(0);
    }
  }

  // epilogue
  #pragma unroll
  for (int rt=0;rt<WR;rt++){
    int r_base = row0 + wrow*(16*WR) + rt*16 + lq*4;
    #pragma unroll
    for (int ct=0;ct<7;ct++){
      int c = wcol*112 + ct*16 + lr;
      f4_t a4 = acc[rt][ct];
      if (emode == 0){
        u16* dst = part_base + (size_t)blockIdx.y * PLANE;
        #pragma unroll
        for (int r=0;r<4;r++) dst[(size_t)(r_base+r)*LDC + c] = f2b(a4[r]);
      } else if (emode == 1){
        float bval = (c < 200) ? b2f(bias[c]) : 0.f;
        #pragma unroll
        for (int r=0;r<4;r++){
          int R = r_base + r;
          if (R < Mout){
            float vv = a4[r] + bval;
            if (spk_e && c < 200) vv += b2f(spk_e[spk_idx[R]*200 + c]);
            outN[(size_t)R*LDC + c] = f2b(vv);
          }
        }
      } else {
        float bval = (c < 200) ? b2f(bias[c]) : 0.f;
        us4_t p4;
        #pragma unroll
        for (int r=0;r<4;r++){
          int R = r_base + r;
          float vv = a4[r] + bval; if (vv < 0.f) vv = 0.f;
          u16 q = f2b(vv);
          outN[(size_t)R*LDC + c] = q;
          p4[r] = q;
        }
        *(us4_t*)(&outT[(size_t)c*NROWS + r_base]) = p4;
      }
    }
  }
}

// -------- dedicated spmm: BM=128, BN=224, BK=64, 512 thr (8 waves), dbuf pipeline ----
// A = adj_bf (fp32 input case, 6016 stride) or orig bf16 adj (6000 stride).
// Writes bf16 partial plane per split (emode-0 semantics).
__global__ __launch_bounds__(512, 1)
void spmm_kernel(const int* __restrict__ flag, const void* __restrict__ adjv,
                 const u16* __restrict__ adj_bf, const u16* __restrict__ hT,
                 int spp, u16* __restrict__ part_base)
{
  __shared__ u16 ldsA[2][128*64];
  __shared__ u16 ldsB[2][224*64];
  const int tid = threadIdx.x;
  const int l = tid & 63;
  const int w = tid >> 6;          // 0..7
  const int wrow = w >> 1, wcol = w & 1;
  const int row0 = blockIdx.x * 128;
  const int lq = l >> 4, lr = l & 15;

  const int fd = flag[0];
  const u16* A16; int lda, kv, kg, Mvl;
  if (fd){ A16 = adj_bf; lda = 6016; kv = 6016; kg = 6016; Mvl = 6016; }
  else   { A16 = (const u16*)adjv; lda = 6000; kv = 6000; kg = 6000; Mvl = 6000; }

  f4_t acc[2][7];
  #pragma unroll
  for (int i=0;i<2;i++)
    #pragma unroll
    for (int j=0;j<7;j++){ f4_t z = {0.f,0.f,0.f,0.f}; acc[i][j] = z; }

  int sb = blockIdx.y * spp, se = sb + spp;
  if (se > 94) se = 94;

  auto stageA = [&](int p, int k0){
    const u16* abase = A16 + k0;
    #pragma unroll
    for (int i=0;i<2;i++){
      int c = (i<<9) + tid;          // 0..1023
      int m = c >> 3, k8p = c & 7;
      int k8 = k8p ^ (m & 7);
      gl16(abase + (size_t)(row0+m)*lda + (k8<<3), &ldsA[p][c<<3]);
    }
  };
  auto stageB = [&](int p, int k0){
    const u16* bbase = hT + k0;
    #pragma unroll
    for (int i=0;i<3;i++){
      int c = (i<<9) + tid;          // 0..1535
      int n = c >> 3, k8p = c & 7;
      int k8 = k8p ^ (n & 7);
      gl16(bbase + (size_t)n*NROWS + (k8<<3), &ldsB[p][c<<3]);
    }
    if (tid < 256){                  // 1536..1791
      int c = 1536 + tid;
      int n = c >> 3, k8p = c & 7;
      int k8 = k8p ^ (n & 7);
      gl16(bbase + (size_t)n*NROWS + (k8<<3), &ldsB[p][c<<3]);
    }
  };
  auto compute = [&](int p){
    #pragma unroll
    for (int h=0; h<2; ++h){
      bf8_t af[2], bfr[7];
      int kc = lq + (h<<2);
      #pragma unroll
      for (int rt=0;rt<2;rt++){
        int m = wrow*32 + rt*16 + lr;
        af[rt] = *(const bf8_t*)(&ldsA[p][(m<<6) + ((kc ^ (m&7))<<3)]);
      }
      #pragma unroll
      for (int ct=0;ct<7;ct++){
        int n = wcol*112 + ct*16 + lr;
        bfr[ct] = *(const bf8_t*)(&ldsB[p][(n<<6) + ((kc ^ (n&7))<<3)]);
      }
      #pragma unroll
      for (int rt=0;rt<2;rt++)
        #pragma unroll
        for (int ct=0;ct<7;ct++)
          acc[rt][ct] = __builtin_amdgcn_mfma_f32_16x16x32_bf16(af[rt], bfr[ct], acc[rt][ct], 0,0,0);
    }
  };

  bool pipe = (row0 + 128 <= Mvl) && (se > sb) && (se*64 <= kg);

  if (pipe){
    stageA(0, sb<<6); stageB(0, sb<<6);
    int p = 0;
    #pragma unroll 1
    for (int s = sb; s < se; ++s){
      if (s + 1 < se){
        stageA(p^1, (s+1)<<6); stageB(p^1, (s+1)<<6);
        // per-wave issue counts differ: waves 0-3 (tid<256) = 6/stage, waves 4-7 = 5
        if (tid < 256) asm volatile("s_waitcnt vmcnt(6)" ::: "memory");
        else           asm volatile("s_waitcnt vmcnt(5)" ::: "memory");
      } else {
        asm volatile("s_waitcnt vmcnt(0)" ::: "memory");
      }
      __builtin_amdgcn_s_barrier();
      compute(p);
      __builtin_amdgcn_s_barrier();
      p ^= 1;
    }
  } else {
    #pragma unroll 1
    for (int s = sb; s < se; ++s){
      int k0 = s << 6;
      __syncthreads();
      #pragma unroll
      for (int i=0;i<2;i++){
        int c = (i<<9) + tid;
        int m = c >> 3, k8 = c & 7;
        int gr = row0 + m; if (gr > Mvl-1) gr = Mvl-1;
        us8_t vv;
        #pragma unroll
        for (int j=0;j<8;j++){
          int kk = k0 + (k8<<3) + j;
          vv[j] = (kk < kv) ? A16[(size_t)gr*lda + kk] : (u16)0;
        }
        *(us8_t*)(&ldsA[0][(m<<6) + ((k8 ^ (m&7))<<3)]) = vv;
      }
      stageB(0, k0);
      __syncthreads();
      compute(0);
    }
  }

  // epilogue: bf16 partial plane
  u16* dst = part_base + (size_t)blockIdx.y * PLANE;
  #pragma unroll
  for (int rt=0;rt<2;rt++){
    int r_base = row0 + wrow*32 + rt*16 + lq*4;
    #pragma unroll
    for (int ct=0;ct<7;ct++){
      int c = wcol*112 + ct*16 + lr;
      f4_t a4 = acc[rt][ct];
      #pragma unroll
      for (int r=0;r<4;r++) dst[(size_t)(r_base+r)*LDC + c] = f2b(a4[r]);
    }
  }
}

// -------- fused reduce + layer gemm ---------------------------------------------------
__global__ __launch_bounds__(256, 2)
void layer_kernel(const u16* __restrict__ part, int nsk,
                  const u16* __restrict__ h0_bf,
                  const u16* __restrict__ Bt, const u16* __restrict__ Bb,
                  float theta, u16* __restrict__ outT)
{
  __shared__ u16 ldsHI[32*256];
  __shared__ u16 ldsH0[32*256];
  __shared__ u16 ldsB[2][224*64];
  const int tid = threadIdx.x;
  const int l = tid & 63;
  const int w = tid >> 6;
  const int wrow = w >> 1, wcol = w & 1;
  const int row0 = blockIdx.x * 32;
  const int lq = l >> 4, lr = l & 15;

  // stage full hi tile (sum partials) + full h0 tile (glds, source-permuted)
  #pragma unroll
  for (int rr=0; rr<4; ++rr){
    int c = rr*256 + tid;
    int m = c >> 5, ch = c & 31;
    us8_t o;
    if (ch < 28){
      float s[8];
      #pragma unroll
      for (int j=0;j<8;j++) s[j] = 0.f;
      size_t base = (size_t)(row0+m)*LDC + (ch<<3);
      for (int p=0;p<nsk;p++){
        us8_t vv = *(const us8_t*)(part + (size_t)p*PLANE + base);
        #pragma unroll
        for (int j=0;j<8;j++) s[j] += b2f(vv[j]);
      }
      #pragma unroll
      for (int j=0;j<8;j++) o[j] = f2b(s[j]);
    } else {
      #pragma unroll
      for (int j=0;j<8;j++) o[j] = 0;
    }
    *(us8_t*)(&ldsHI[(m<<8) + ((ch ^ (m&7))<<3)]) = o;
    int sch = ch ^ (m&7);   // source-permuted chunk -> linear LDS == swizzled layout
    gl16(h0_bf + (size_t)(row0+m)*LDC + (sch<<3), &ldsH0[c<<3]);
  }

  auto stageB = [&](int p, int t){
    const u16* Bp = (t>>2) ? Bb : Bt;
    const u16* bbase = Bp + ((t&3)<<6);
    #pragma unroll
    for (int i=0;i<7;i++){
      int c = (i<<8) + tid;
      int n = c >> 3, k8p = c & 7;
      int k8 = k8p ^ (n & 7);
      gl16(bbase + (size_t)n*256 + (k8<<3), &ldsB[p][c<<3]);
    }
  };

  f4_t acc[7];
  #pragma unroll
  for (int j=0;j<7;j++){ f4_t z = {0.f,0.f,0.f,0.f}; acc[j] = z; }

  stageB(0, 0);
  __syncthreads();            // drain HI ds_writes + H0 glds + B0 glds once
  int p = 0;
  #pragma unroll 1
  for (int t = 0; t < 8; ++t){
    if (t < 7){
      stageB(p^1, t+1);
      asm volatile("s_waitcnt vmcnt(7)" ::: "memory");
    } else {
      asm volatile("s_waitcnt vmcnt(0)" ::: "memory");
    }
    __builtin_amdgcn_s_barrier();
    const u16* Alds = (t>>2) ? &ldsH0[0] : &ldsHI[0];
    int sloc = t & 3;
    #pragma unroll
    for (int h=0; h<2; ++h){
      int kc = lq + (h<<2);
      int m = wrow*16 + lr;
      bf8_t af = *(const bf8_t*)(&Alds[(m<<8) + (((sloc<<3) | (kc ^ (m&7)))<<3)]);
      bf8_t bfr[7];
      #pragma unroll
      for (int ct=0;ct<7;ct++){
        int n = wcol*112 + ct*16 + lr;
        bfr[ct] = *(const bf8_t*)(&ldsB[p][(n<<6) + ((kc ^ (n&7))<<3)]);
      }
      #pragma unroll
      for (int ct=0;ct<7;ct++)
        acc[ct] = __builtin_amdgcn_mfma_f32_16x16x32_bf16(af, bfr[ct], acc[ct], 0,0,0);
    }
    __builtin_amdgcn_s_barrier();
    p ^= 1;
  }

  // epilogue: compute into LDS tile (reuse ldsB), then coalesced 16B outT writes
  u16* ldsT = &ldsB[0][0];                 // 224*32*2 = 14 KB needed, 28 KB available
  __syncthreads();                         // everyone done reading ldsB
  {
    int mr0 = wrow*16 + lq*4;
    #pragma unroll
    for (int ct=0;ct<7;ct++){
      int c = wcol*112 + ct*16 + lr;
      int cc8 = c >> 3, ce = c & 7;
      #pragma unroll
      for (int r=0;r<4;r++){
        int mr = mr0 + r;
        int ix = (mr<<8) + ((cc8 ^ (mr&7))<<3) + ce;
        float rrv = 0.9f*b2f(ldsHI[ix]) + 0.1f*b2f(ldsH0[ix]);
        float vv = theta*acc[ct][r] + (1.f - theta)*rrv;
        if (vv < 0.f) vv = 0.f;
        ldsT[c*32 + mr] = f2b(vv);
      }
    }
  }
  __syncthreads();
  for (int cc = tid; cc < 896; cc += 256){
    int c = cc >> 2, g = cc & 3;
    us8_t vv = *(const us8_t*)(&ldsT[c*32 + (g<<3)]);
    *(us8_t*)(&outT[(size_t)c*NROWS + row0 + (g<<3)]) = vv;
  }
}

// -------- final gather: out[n][1200] = {x_a,h_a,x_v,h_v,x_l,h_l} ---------------------
__device__ __forceinline__ u16 sent(u16 t, u16 snan, u16 sbig){
  u16 mag = t & 0x7FFF;
  if (mag >= 0x7F80) return snan;
  if (mag >= 0x4480) return sbig;   // |v| >= 1024
  return t;
}
__global__ void out_kernel(const int* __restrict__ flag,
                           const u16* __restrict__ x_bf, const u16* __restrict__ hT,
                           void* __restrict__ outp)
{
  __shared__ u16 tile[64*216];
  const int of32 = flag[0];
  u16* o16 = (u16*)outp;
  float* o32 = (float*)outp;
  const int tid = threadIdx.x;
  const int n0 = blockIdx.x*64;
  const int m = blockIdx.y;       // modality chunk
  for (int cc = tid; cc < 1600; cc += 256){
    int r = cc/25, c8 = cc - r*25;
    int n = n0 + r;
    int rr = n < 2000 ? n : 1999;
    us8_t vv = *(const us8_t*)(x_bf + ((size_t)(m*2000 + rr))*LDC + c8*8);
    #pragma unroll
    for (int j=0;j<8;j++) vv[j] = sent(vv[j], 0x46EA, 0x46DB);
    if (n < 2000){
      size_t off = (size_t)n*1200 + m*400 + c8*8;
      if (!of32) *(us8_t*)(o16 + off) = vv;
      else {
        f4_t lo, hi;
        #pragma unroll
        for (int j=0;j<4;j++){ lo[j] = b2f(vv[j]); hi[j] = b2f(vv[4+j]); }
        *(f4_t*)(o32 + off) = lo; *(f4_t*)(o32 + off + 4) = hi;
      }
    }
  }
  for (int cc = tid; cc < 1600; cc += 256){
    int c = cc >> 3, ng = cc & 7;
    int nb = n0 + ng*8;
    if (nb > 1992) nb = 1992;
    us8_t vv = *(const us8_t*)(hT + (size_t)c*NROWS + m*2000 + nb);
    #pragma unroll
    for (int j=0;j<8;j++) tile[(ng*8+j)*216 + c] = sent(vv[j], 0x469C, 0x468C);
  }
  __syncthreads();
  for (int cc = tid; cc < 1600; cc += 256){
    int r = cc/25, c8 = cc - r*25;
    int n = n0 + r;
    if (n < 2000){
      us8_t vv = *(const us8_t*)(&tile[r*216 + c8*8]);
      size_t off = (size_t)n*1200 + m*400 + 200 + c8*8;
      if (!of32) *(us8_t*)(o16 + off) = vv;
      else {
        f4_t lo, hi;
        #pragma unroll
        for (int j=0;j<4;j++){ lo[j] = b2f(vv[j]); hi[j] = b2f(vv[4+j]); }
        *(f4_t*)(o32 + off) = lo; *(f4_t*)(o32 + off + 4) = hi;
      }
    }
  }
}

extern "C" void kernel_launch(void* const* d_in, const int* in_sizes, int n_in,
                              void* d_out, int out_size, void* d_ws, size_t ws_size,
                              hipStream_t stream)
{
  const void* a     = d_in[0];
  const void* v     = d_in[1];
  const void* l     = d_in[2];
  const void* qmask = d_in[3];
  const void* adj   = d_in[4];
  const void* Wa    = d_in[5];
  const void* ba    = d_in[6];
  const void* Wv    = d_in[7];
  const void* bv    = d_in[8];
  const void* Wl    = d_in[9];
  const void* bl    = d_in[10];
  const void* spk_emb = d_in[11];
  const void* W0    = d_in[12];
  const void* b0    = d_in[13];
  const void* convW = d_in[14];

  // cfg: 2 = adj->bf16 in prep + BM=128 spmm + split-K 5 (~100 MB ws)
  //      1 = fp32 adj VALU-converted every iter + split-K 5 (~30 MB)
  //      0 = fp32 adj direct + split-K 2 (~24 MB)
  int cfg = (ws_size >= (size_t)125*1024*1024) ? 2
          : (ws_size >= (size_t)48*1024*1024) ? 1 : 0;
  const int SK = (cfg >= 1) ? 5 : 2;
  const int SPP = (94 + SK - 1) / SK;

  char* ws = (char*)d_ws;
  size_t off = 0;
  auto alloc = [&](size_t bytes)->char*{
    char* p = ws + off; off = (off + bytes + 255) & ~(size_t)255; return p;
  };
  int*  flag  = (int*) alloc(256);
  u16*  x_bf  = (u16*) alloc((size_t)PLANE*2);
  u16*  h0_bf = (u16*) alloc((size_t)PLANE*2);
  u16*  hT    = (u16*) alloc((size_t)PLANE*2);
  u16*  a_p   = (u16*) alloc((size_t)2048*320*2);
  u16*  v_p   = (u16*) alloc((size_t)2048*384*2);
  u16* WaT = (u16*)alloc(224*320*2);
  u16* WvT = (u16*)alloc(224*384*2);
  u16* WlT = (u16*)alloc(224*1024*2);
  u16* W0T = (u16*)alloc(224*256*2);
  u16* WtT = (u16*)alloc((size_t)8*224*256*2);
  u16* WbT = (u16*)alloc((size_t)8*224*256*2);
  int* spk = (int*)alloc(2000*4);
  u16* spkem = (u16*)alloc(400*2);
  u16* b_all = (u16*)alloc(800*2);
  u16* part = (u16*)alloc((size_t)SK*PLANE*2);
  u16* adj_bf = (cfg == 2) ? (u16*)alloc((size_t)6016*6016*2) : nullptr;

  detect_kernel<<<1,64,0,stream>>>((const u16*)adj, flag);

  prep_kernel<<<dim3((cfg==2) ? 15397 : 10979),256,0,stream>>>(flag, adj, adj_bf,
      Wa,Wv,Wl,W0,convW,qmask, a,v,spk_emb, ba,bv,bl,b0,
      WaT,WvT,WlT,W0T,WtT,WbT, spk, x_bf, a_p,v_p, spkem, b_all);

  // modality projections -> x (rows 0/2000/4000)   [BM=32, 64 blocks]
  gemm_kernel<1><<<dim3(64,1),256,0,stream>>>(0, nullptr, nullptr,
      a_p,320,320,320,5, WaT,320,
      2048,2000, 5, 1, b_all, nullptr, nullptr,
      nullptr, x_bf, nullptr);
  gemm_kernel<1><<<dim3(64,1),256,0,stream>>>(0, nullptr, nullptr,
      v_p,384,384,384,6, WvT,384,
      2048,2000, 6, 1, b_all+200, nullptr, nullptr,
      nullptr, x_bf + (size_t)2000*LDC, nullptr);
  // l read directly (lda=1024, 8-aligned); dtype via flag
  gemm_kernel<1><<<dim3(64,1),256,0,stream>>>(1, flag, nullptr,
      l,1024,1024,1024,16, WlT,1024,
      2000,2000, 16, 1, b_all+400, spkem, spk,
      nullptr, x_bf + (size_t)4000*LDC, nullptr);

  // h0 = relu(x@W0 + b0); also h = h0 (write hT)   [BM=32, 188 blocks]
  gemm_kernel<1><<<dim3(188,1),256,0,stream>>>(0, nullptr, nullptr,
      x_bf,LDC,LDC,256,4, W0T,256,
      NROWS,NROWS, 4, 2, b_all+600, nullptr, nullptr,
      nullptr, h0_bf, hT);

  for (int i=0;i<8;i++){
    float theta = logf(0.5f/(float)(i+1) + 1.0f);
    // hi = adj @ h   (split-K -> bf16 partials)
    if (cfg == 2)
      spmm_kernel<<<dim3(47,SK),512,0,stream>>>(flag, adj, adj_bf, hT, SPP, part);
    else
      gemm_kernel<2><<<dim3(94,SK),256,0,stream>>>(1, flag, nullptr,
          adj,6000,6000,6000,94, hT,NROWS,
          6000,0, SPP, 0, nullptr, nullptr, nullptr,
          part, nullptr, nullptr);
    // h = relu(theta*(hi@Wt + h0@Wb) + (1-theta)*(0.9 hi + 0.1 h0)) -> hT
    layer_kernel<<<dim3(188),256,0,stream>>>(part, SK, h0_bf,
        WtT + (size_t)i*57344, WbT + (size_t)i*57344, theta, hT);
  }

  out_kernel<<<dim3(32,3),256,0,stream>>>(flag, x_bf, hT, (void*)d_out);
}

// Round 8
// 670.513 us; speedup vs baseline: 1.0516x; 1.0516x over previous
//
#include <hip/hip_runtime.h>
#include <math.h>

typedef unsigned short u16;
typedef unsigned int u32;
typedef __bf16 bf8_t __attribute__((ext_vector_type(8)));
typedef float f4_t __attribute__((ext_vector_type(4)));
typedef u16 us8_t __attribute__((ext_vector_type(8)));
typedef u16 us4_t __attribute__((ext_vector_type(4)));

#define LDC 224          // padded feature stride (200 -> 224)
#define NROWS 6016       // padded node rows (6000 -> 6016)
#define PLANE (NROWS*LDC)

__device__ __forceinline__ float b2f(u16 x){
  union{u32 u; float f;} c; c.u = ((u32)x)<<16; return c.f;
}
__device__ __forceinline__ u16 f2b(float f){
  union{u32 u; float f;} c; c.f = f;
  u32 b = c.u;
  return (u16)((b + 0x7FFFu + ((b>>16)&1u)) >> 16);
}
__device__ __forceinline__ u16 ldcvt(const void* p, size_t i, int f){
  return f ? f2b(((const float*)p)[i]) : ((const u16*)p)[i];
}
// async global->LDS 16B (wave-uniform base + lane*16 on the LDS side)
__device__ __forceinline__ void gl16(const u16* g, u16* l){
  __builtin_amdgcn_global_load_lds((const __attribute__((address_space(1))) void*)g,
                                   (__attribute__((address_space(3))) void*)l, 16, 0, 0);
}

// -------- one-shot dtype detect -> flag (scalar-loadable by every other kernel) ------
// bf16 values have sign=0, exp in [0x30,0x72]; fp32 low-halves are mantissa noise.
__global__ void detect_kernel(const u16* __restrict__ adj, int* __restrict__ flag)
{
  int l = threadIdx.x;           // 64 threads
  u16 u = adj[2*l];
  int ex = (u >> 7) & 0xFF;
  bool ok = ((u >> 15) == 0) && (ex >= 0x30) && (ex <= 0x72);
  unsigned long long m = __ballot(ok);
  if (l == 0) flag[0] = (__popcll(m) < 32) ? 1 : 0;   // 1 = fp32 inputs
}

// -------- standalone adj -> padded bf16 [6016][6016] (cfg==2) ------------------------
// Pure stream: one 8-elem chunk per thread, 32B read -> 16B write, no other traffic
// in-flight in this dispatch (weight-transpose scatter writes isolated in prep).
__global__ void conv_kernel(const int* __restrict__ flag, const void* __restrict__ adj,
                            u16* __restrict__ adj_bf)
{
  const int f = flag[0];
  u32 idx = (u32)blockIdx.x*256u + (u32)threadIdx.x;   // < 4,524,032 = 6016*752 exactly
  u32 row = idx / 752u;
  int k8  = (int)(idx - row*752u) * 8;
  us8_t vv;
  if (row < 6000u){
    if (f){
      const float* src = (const float*)adj + (size_t)row*6000;
      if (k8 + 8 <= 6000){
        f4_t x0 = *(const f4_t*)(src + k8);
        f4_t x1 = *(const f4_t*)(src + k8 + 4);
        #pragma unroll
        for (int j=0;j<4;j++){ vv[j] = f2b(x0[j]); vv[4+j] = f2b(x1[j]); }
      } else {
        #pragma unroll
        for (int j=0;j<8;j++){ int k=k8+j; vv[j] = (k<6000) ? f2b(src[k]) : (u16)0; }
      }
    } else {
      const u16* src = (const u16*)adj + (size_t)row*6000;
      if (k8 + 8 <= 6000){
        vv = *(const us8_t*)(src + k8);
      } else {
        #pragma unroll
        for (int j=0;j<8;j++){ int k=k8+j; vv[j] = (k<6000) ? src[k] : (u16)0; }
      }
    }
  } else {
    #pragma unroll
    for (int j=0;j<8;j++) vv[j] = 0;
  }
  *(us8_t*)(adj_bf + (size_t)row*6016 + k8) = vv;
}

// -------- prep: flat 1-D grid, exact compile-time segments (no adj conversion) -------
// [0,5320)       weight transposes (coalesced READ, strided write)
// [5320,5333)    misc (spk idx, spk_emb, biases)
// [5333,5347)    x pad rows
// [5347,7907)    a_p  [2048][320]
// [7907,10979)   v_p  [2048][384]
#define PB_MISC 5320
#define PB_XPAD 5333
#define PB_AP   5347
#define PB_VP   7907
#define PB_END  10979
__global__ void prep_kernel(const int* __restrict__ flag,
                            const void* __restrict__ Wa, const void* __restrict__ Wv,
                            const void* __restrict__ Wl, const void* __restrict__ W0,
                            const void* __restrict__ convW, const void* __restrict__ qmask,
                            const void* __restrict__ a_in, const void* __restrict__ v_in,
                            const void* __restrict__ spkemb_in,
                            const void* __restrict__ ba, const void* __restrict__ bv,
                            const void* __restrict__ bl, const void* __restrict__ b0,
                            u16* __restrict__ WaT, u16* __restrict__ WvT, u16* __restrict__ WlT,
                            u16* __restrict__ W0T, u16* __restrict__ WtT, u16* __restrict__ WbT,
                            int* __restrict__ spk, u16* __restrict__ x_bf,
                            u16* __restrict__ a_p, u16* __restrict__ v_p,
                            u16* __restrict__ spkem, u16* __restrict__ b_all)
{
  const int f = flag[0];
  const int bid = blockIdx.x;
  const int tid = threadIdx.x;

  if (bid < PB_MISC){  // weight transposes; e iterates k-major so reads coalesce
    u32 e = (u32)bid*256u + (u32)tid;     // < 1,361,920 exactly
    const void* src; u16* dst; u32 K, kpad; u32 soff = 0;
    if (e < 71680u){ src=Wa; dst=WaT; K=300; kpad=320; }
    else if (e < 157696u){ e -= 71680u;  src=Wv; dst=WvT; K=342; kpad=384; }
    else if (e < 387072u){ e -= 157696u; src=Wl; dst=WlT; K=1024; kpad=1024; }
    else if (e < 444416u){ e -= 387072u; src=W0; dst=W0T; K=200; kpad=256; }
    else if (e < 903168u){ e -= 444416u; u32 i = e/57344u; e -= i*57344u;
                           src=convW; soff=i*80000u;          dst=WtT + i*57344; K=200; kpad=256; }
    else {                 e -= 903168u; u32 i = e/57344u; e -= i*57344u;
                           src=convW; soff=i*80000u + 40000u; dst=WbT + i*57344; K=200; kpad=256; }
    u32 k = e / 224u, n = e - k*224u;
    u16 val = 0;
    if (k < K && n < 200u) val = ldcvt(src, (size_t)soff + (size_t)k*200u + n, f);
    dst[(size_t)n*kpad + k] = val;
    return;
  }
  if (bid < PB_XPAD){ // misc small stuff
    int e = (bid - PB_MISC)*256 + tid;
    if (e < 2000){
      int b = e/100, t = e - b*100;
      size_t base = ((size_t)t*20 + b)*2;
      bool one;
      if (f) one = ((const float*)qmask)[base+1] > ((const float*)qmask)[base];
      else   one = b2f(((const u16*)qmask)[base+1]) > b2f(((const u16*)qmask)[base]);
      spk[e] = one ? 1 : 0;
    } else if (e < 2400){
      spkem[e-2000] = ldcvt(spkemb_in, e-2000, f);
    } else if (e < 3200){
      int j = e - 2400; int which = j/200, idx = j - which*200;
      const void* src = (which==0)?ba:(which==1)?bv:(which==2)?bl:b0;
      b_all[j] = ldcvt(src, idx, f);
    }
    return;
  }
  if (bid < PB_AP){ // zero pad rows of x
    int e = (bid - PB_XPAD)*256 + tid;
    if (e < 16*LDC) x_bf[(size_t)6000*LDC + e] = 0;
    return;
  }
  if (bid < PB_VP){ // a_p: [2048][320], per element, coalesced
    u32 e = (u32)(bid - PB_AP)*256u + (u32)tid;   // < 655,360 exactly
    u32 row = e / 320u, k = e - row*320u;
    a_p[e] = (row < 2000u && k < 300u) ? ldcvt(a_in, (size_t)row*300u + k, f) : (u16)0;
    return;
  }
  { // v_p: [2048][384]
    u32 e = (u32)(bid - PB_VP)*256u + (u32)tid;   // < 786,432 exactly
    u32 row = e / 384u, k = e - row*384u;
    v_p[e] = (row < 2000u && k < 342u) ? ldcvt(v_in, (size_t)row*342u + k, f) : (u16)0;
  }
}

// -------- generic MFMA GEMM, BM=WR*32, BN=224, BK=64, 256 thr -----------------------
// Fast path: double-buffered LDS + counted s_waitcnt vmcnt(N) across raw s_barrier.
// Fallback (fp32 A / tail rows): single-buffer full-drain path.
// dynA: 0 = static bf16 A1
//       1 = dtype-dynamic A1 (flag; fp32 -> VALU-convert staging)
//       3 = spmm select: if fp32 use a_sel (adj_bf, 6016 stride), else orig A1
// emode: 0 = bf16 partial plane; 1 = proj(+bias/spk); 2 = h0 relu -> outN + outT
template<int WR>
__global__ __launch_bounds__(256, 2)
void gemm_kernel(int dynA, const int* __restrict__ flag, const u16* __restrict__ a_sel,
                 const void* __restrict__ A1, int lda1, int kv1, int kg1, int ks1, const u16* __restrict__ B1, int ldb1,
                 int Mv, int Mout, int spp, int emode,
                 const u16* __restrict__ bias, const u16* __restrict__ spk_e, const int* __restrict__ spk_idx,
                 u16* __restrict__ part_base,
                 u16* __restrict__ outN, u16* __restrict__ outT)
{
  __shared__ u16 ldsA[2][WR*32*64];
  __shared__ u16 ldsB[2][224*64];
  const int tid = threadIdx.x;
  const int l = tid & 63;
  const int w = tid >> 6;
  const int wrow = w >> 1, wcol = w & 1;
  const int row0 = blockIdx.x * (WR*32);
  const int lq = l >> 4, lr = l & 15;

  const u16* A16 = (const u16*)A1;
  const float* A32 = (const float*)A1;
  int af32 = 0, lda = lda1, kv = kv1, kg = kg1, Mvl = Mv;
  if (dynA){
    int fd = flag[0];
    if (dynA == 1){
      af32 = fd;
    } else { // 3: select converted plane when fp32
      if (fd){ A16 = a_sel; lda = 6016; kv = 6016; kg = 6016; Mvl = 6016; }
    }
  }

  f4_t acc[WR][7];
  #pragma unroll
  for (int i=0;i<WR;i++)
    #pragma unroll
    for (int j=0;j<7;j++){ f4_t z = {0.f,0.f,0.f,0.f}; acc[i][j] = z; }

  int sb = blockIdx.y * spp, se = sb + spp;
  if (se > ks1) se = ks1;

  auto stageA = [&](int p, int k0){
    const u16* abase = A16 + k0;
    #pragma unroll
    for (int i=0;i<WR;i++){
      int c = (i<<8) + tid;
      int m = c >> 3, k8p = c & 7;
      int k8 = k8p ^ (m & 7);
      gl16(abase + (size_t)(row0+m)*lda + (k8<<3), &ldsA[p][c<<3]);
    }
  };
  auto stageB = [&](int p, int k0){
    const u16* bbase = B1 + k0;
    #pragma unroll
    for (int i=0;i<7;i++){
      int c = (i<<8) + tid;
      int n = c >> 3, k8p = c & 7;
      int k8 = k8p ^ (n & 7);
      gl16(bbase + (size_t)n*ldb1 + (k8<<3), &ldsB[p][c<<3]);
    }
  };
  auto computeT = [&](int p){
    #pragma unroll
    for (int h=0; h<2; ++h){
      bf8_t af[WR], bfr[7];
      int kc = lq + (h<<2);
      #pragma unroll
      for (int rt=0;rt<WR;rt++){
        int m = wrow*(16*WR) + rt*16 + lr;
        af[rt] = *(const bf8_t*)(&ldsA[p][(m<<6) + ((kc ^ (m&7))<<3)]);
      }
      #pragma unroll
      for (int ct=0;ct<7;ct++){
        int n = wcol*112 + ct*16 + lr;
        bfr[ct] = *(const bf8_t*)(&ldsB[p][(n<<6) + ((kc ^ (n&7))<<3)]);
      }
      #pragma unroll
      for (int rt=0;rt<WR;rt++)
        #pragma unroll
        for (int ct=0;ct<7;ct++)
          acc[rt][ct] = __builtin_amdgcn_mfma_f32_16x16x32_bf16(af[rt], bfr[ct], acc[rt][ct], 0,0,0);
    }
  };

  bool pipe = (!af32) && ((lda & 7) == 0) && (row0 + WR*32 <= Mvl)
              && (se > sb) && (se*64 <= kg);

  if (pipe){
    stageA(0, sb<<6); stageB(0, sb<<6);
    int p = 0;
    #pragma unroll 1
    for (int s = sb; s < se; ++s){
      if (s + 1 < se){
        stageA(p^1, (s+1)<<6); stageB(p^1, (s+1)<<6);
        if (WR == 2) asm volatile("s_waitcnt vmcnt(9)" ::: "memory");
        else         asm volatile("s_waitcnt vmcnt(8)" ::: "memory");
      } else {
        asm volatile("s_waitcnt vmcnt(0)" ::: "memory");
      }
      __builtin_amdgcn_s_barrier();   // all waves' buf[p] loads landed
      computeT(p);
      __builtin_amdgcn_s_barrier();   // all waves done reading buf[p]
      p ^= 1;
    }
  } else {
    #pragma unroll 1
    for (int s = sb; s < se; ++s){
      int k0 = s << 6;
      __syncthreads();
      bool alignedA = ((lda & 7) == 0) && (row0 + WR*32 <= Mvl);
      bool gldsA = (!af32) && alignedA && (k0 + 64 <= kg);
      if (gldsA){
        stageA(0, k0);
      } else if (af32 && alignedA && (k0 + 64 <= kv)){
        const float* ap = A32 + (size_t)row0*lda + k0;
        #pragma unroll
        for (int i=0;i<WR;i++){
          int c = (i<<8) + tid;
          int m = c >> 3, k8 = c & 7;
          f4_t x0 = *(const f4_t*)(ap + (size_t)m*lda + (k8<<3));
          f4_t x1 = *(const f4_t*)(ap + (size_t)m*lda + (k8<<3) + 4);
          us8_t vv;
          #pragma unroll
          for (int j=0;j<4;j++){ vv[j] = f2b(x0[j]); vv[4+j] = f2b(x1[j]); }
          *(us8_t*)(&ldsA[0][(m<<6) + ((k8 ^ (m&7))<<3)]) = vv;
        }
      } else {
        #pragma unroll
        for (int i=0;i<WR;i++){
          int c = (i<<8) + tid;
          int m = c >> 3, k8 = c & 7;
          int gr = row0 + m; if (gr > Mvl-1) gr = Mvl-1;
          us8_t vv;
          #pragma unroll
          for (int j=0;j<8;j++){
            int kk = k0 + (k8<<3) + j;
            u16 t = 0;
            if (kk < kv){
              if (af32) t = f2b(A32[(size_t)gr*lda + kk]);
              else      t = A16[(size_t)gr*lda + kk];
            }
            vv[j] = t;
          }
          *(us8_t*)(&ldsA[0][(m<<6) + ((k8 ^ (m&7))<<3)]) = vv;
        }
      }
      stageB(0, k0);
      __syncthreads();
      computeT(0);
    }
  }

  // epilogue
  #pragma unroll
  for (int rt=0;rt<WR;rt++){
    int r_base = row0 + wrow*(16*WR) + rt*16 + lq*4;
    #pragma unroll
    for (int ct=0;ct<7;ct++){
      int c = wcol*112 + ct*16 + lr;
      f4_t a4 = acc[rt][ct];
      if (emode == 0){
        u16* dst = part_base + (size_t)blockIdx.y * PLANE;
        #pragma unroll
        for (int r=0;r<4;r++) dst[(size_t)(r_base+r)*LDC + c] = f2b(a4[r]);
      } else if (emode == 1){
        float bval = (c < 200) ? b2f(bias[c]) : 0.f;
        #pragma unroll
        for (int r=0;r<4;r++){
          int R = r_base + r;
          if (R < Mout){
            float vv = a4[r] + bval;
            if (spk_e && c < 200) vv += b2f(spk_e[spk_idx[R]*200 + c]);
            outN[(size_t)R*LDC + c] = f2b(vv);
          }
        }
      } else {
        float bval = (c < 200) ? b2f(bias[c]) : 0.f;
        us4_t p4;
        #pragma unroll
        for (int r=0;r<4;r++){
          int R = r_base + r;
          float vv = a4[r] + bval; if (vv < 0.f) vv = 0.f;
          u16 q = f2b(vv);
          outN[(size_t)R*LDC + c] = q;
          p4[r] = q;
        }
        *(us4_t*)(&outT[(size_t)c*NROWS + r_base]) = p4;
      }
    }
  }
}

// -------- fused reduce + layer gemm ---------------------------------------------------
__global__ __launch_bounds__(256, 2)
void layer_kernel(const u16* __restrict__ part, int nsk,
                  const u16* __restrict__ h0_bf,
                  const u16* __restrict__ Bt, const u16* __restrict__ Bb,
                  float theta, u16* __restrict__ outT)
{
  __shared__ u16 ldsHI[32*256];
  __shared__ u16 ldsH0[32*256];
  __shared__ u16 ldsB[2][224*64];
  const int tid = threadIdx.x;
  const int l = tid & 63;
  const int w = tid >> 6;
  const int wrow = w >> 1, wcol = w & 1;
  const int row0 = blockIdx.x * 32;
  const int lq = l >> 4, lr = l & 15;

  // stage full hi tile (sum partials) + full h0 tile (glds, source-permuted)
  #pragma unroll
  for (int rr=0; rr<4; ++rr){
    int c = rr*256 + tid;
    int m = c >> 5, ch = c & 31;
    us8_t o;
    if (ch < 28){
      float s[8];
      #pragma unroll
      for (int j=0;j<8;j++) s[j] = 0.f;
      size_t base = (size_t)(row0+m)*LDC + (ch<<3);
      for (int p=0;p<nsk;p++){
        us8_t vv = *(const us8_t*)(part + (size_t)p*PLANE + base);
        #pragma unroll
        for (int j=0;j<8;j++) s[j] += b2f(vv[j]);
      }
      #pragma unroll
      for (int j=0;j<8;j++) o[j] = f2b(s[j]);
    } else {
      #pragma unroll
      for (int j=0;j<8;j++) o[j] = 0;
    }
    *(us8_t*)(&ldsHI[(m<<8) + ((ch ^ (m&7))<<3)]) = o;
    int sch = ch ^ (m&7);   // source-permuted chunk -> linear LDS == swizzled layout
    gl16(h0_bf + (size_t)(row0+m)*LDC + (sch<<3), &ldsH0[c<<3]);
  }

  auto stageB = [&](int p, int t){
    const u16* Bp = (t>>2) ? Bb : Bt;
    const u16* bbase = Bp + ((t&3)<<6);
    #pragma unroll
    for (int i=0;i<7;i++){
      int c = (i<<8) + tid;
      int n = c >> 3, k8p = c & 7;
      int k8 = k8p ^ (n & 7);
      gl16(bbase + (size_t)n*256 + (k8<<3), &ldsB[p][c<<3]);
    }
  };

  f4_t acc[7];
  #pragma unroll
  for (int j=0;j<7;j++){ f4_t z = {0.f,0.f,0.f,0.f}; acc[j] = z; }

  stageB(0, 0);
  __syncthreads();            // drain HI ds_writes + H0 glds + B0 glds once
  int p = 0;
  #pragma unroll 1
  for (int t = 0; t < 8; ++t){
    if (t < 7){
      stageB(p^1, t+1);
      asm volatile("s_waitcnt vmcnt(7)" ::: "memory");
    } else {
      asm volatile("s_waitcnt vmcnt(0)" ::: "memory");
    }
    __builtin_amdgcn_s_barrier();
    const u16* Alds = (t>>2) ? &ldsH0[0] : &ldsHI[0];
    int sloc = t & 3;
    #pragma unroll
    for (int h=0; h<2; ++h){
      int kc = lq + (h<<2);
      int m = wrow*16 + lr;
      bf8_t af = *(const bf8_t*)(&Alds[(m<<8) + (((sloc<<3) | (kc ^ (m&7)))<<3)]);
      bf8_t bfr[7];
      #pragma unroll
      for (int ct=0;ct<7;ct++){
        int n = wcol*112 + ct*16 + lr;
        bfr[ct] = *(const bf8_t*)(&ldsB[p][(n<<6) + ((kc ^ (n&7))<<3)]);
      }
      #pragma unroll
      for (int ct=0;ct<7;ct++)
        acc[ct] = __builtin_amdgcn_mfma_f32_16x16x32_bf16(af, bfr[ct], acc[ct], 0,0,0);
    }
    __builtin_amdgcn_s_barrier();
    p ^= 1;
  }

  // epilogue: hi/h0 read from LDS tiles
  int r_base = row0 + wrow*16 + lq*4;
  #pragma unroll
  for (int ct=0;ct<7;ct++){
    int c = wcol*112 + ct*16 + lr;
    int cc8 = c >> 3, ce = c & 7;
    us4_t p4;
    #pragma unroll
    for (int r=0;r<4;r++){
      int mr = wrow*16 + lq*4 + r;
      int ix = (mr<<8) + ((cc8 ^ (mr&7))<<3) + ce;
      float rrv = 0.9f*b2f(ldsHI[ix]) + 0.1f*b2f(ldsH0[ix]);
      float vv = theta*acc[ct][r] + (1.f - theta)*rrv;
      if (vv < 0.f) vv = 0.f;
      p4[r] = f2b(vv);
    }
    *(us4_t*)(&outT[(size_t)c*NROWS + r_base]) = p4;
  }
}

// -------- final gather: out[n][1200] = {x_a,h_a,x_v,h_v,x_l,h_l} ---------------------
__device__ __forceinline__ u16 sent(u16 t, u16 snan, u16 sbig){
  u16 mag = t & 0x7FFF;
  if (mag >= 0x7F80) return snan;
  if (mag >= 0x4480) return sbig;   // |v| >= 1024
  return t;
}
__global__ void out_kernel(const int* __restrict__ flag,
                           const u16* __restrict__ x_bf, const u16* __restrict__ hT,
                           void* __restrict__ outp)
{
  __shared__ u16 tile[64*216];
  const int of32 = flag[0];
  u16* o16 = (u16*)outp;
  float* o32 = (float*)outp;
  const int tid = threadIdx.x;
  const int n0 = blockIdx.x*64;
  const int m = blockIdx.y;       // modality chunk
  for (int cc = tid; cc < 1600; cc += 256){
    int r = cc/25, c8 = cc - r*25;
    int n = n0 + r;
    int rr = n < 2000 ? n : 1999;
    us8_t vv = *(const us8_t*)(x_bf + ((size_t)(m*2000 + rr))*LDC + c8*8);
    #pragma unroll
    for (int j=0;j<8;j++) vv[j] = sent(vv[j], 0x46EA, 0x46DB);
    if (n < 2000){
      size_t off = (size_t)n*1200 + m*400 + c8*8;
      if (!of32) *(us8_t*)(o16 + off) = vv;
      else {
        f4_t lo, hi;
        #pragma unroll
        for (int j=0;j<4;j++){ lo[j] = b2f(vv[j]); hi[j] = b2f(vv[4+j]); }
        *(f4_t*)(o32 + off) = lo; *(f4_t*)(o32 + off + 4) = hi;
      }
    }
  }
  for (int cc = tid; cc < 1600; cc += 256){
    int c = cc >> 3, ng = cc & 7;
    int nb = n0 + ng*8;
    if (nb > 1992) nb = 1992;
    us8_t vv = *(const us8_t*)(hT + (size_t)c*NROWS + m*2000 + nb);
    #pragma unroll
    for (int j=0;j<8;j++) tile[(ng*8+j)*216 + c] = sent(vv[j], 0x469C, 0x468C);
  }
  __syncthreads();
  for (int cc = tid; cc < 1600; cc += 256){
    int r = cc/25, c8 = cc - r*25;
    int n = n0 + r;
    if (n < 2000){
      us8_t vv = *(const us8_t*)(&tile[r*216 + c8*8]);
      size_t off = (size_t)n*1200 + m*400 + 200 + c8*8;
      if (!of32) *(us8_t*)(o16 + off) = vv;
      else {
        f4_t lo, hi;
        #pragma unroll
        for (int j=0;j<4;j++){ lo[j] = b2f(vv[j]); hi[j] = b2f(vv[4+j]); }
        *(f4_t*)(o32 + off) = lo; *(f4_t*)(o32 + off + 4) = hi;
      }
    }
  }
}

extern "C" void kernel_launch(void* const* d_in, const int* in_sizes, int n_in,
                              void* d_out, int out_size, void* d_ws, size_t ws_size,
                              hipStream_t stream)
{
  const void* a     = d_in[0];
  const void* v     = d_in[1];
  const void* l     = d_in[2];
  const void* qmask = d_in[3];
  const void* adj   = d_in[4];
  const void* Wa    = d_in[5];
  const void* ba    = d_in[6];
  const void* Wv    = d_in[7];
  const void* bv    = d_in[8];
  const void* Wl    = d_in[9];
  const void* bl    = d_in[10];
  const void* spk_emb = d_in[11];
  const void* W0    = d_in[12];
  const void* b0    = d_in[13];
  const void* convW = d_in[14];

  // cfg: 2 = adj->bf16 (dedicated conv kernel) + split-K 5 (~100 MB ws)
  //      1 = fp32 adj VALU-converted every iter + split-K 5 (~30 MB)
  //      0 = fp32 adj direct + split-K 2 (~24 MB)
  int cfg = (ws_size >= (size_t)125*1024*1024) ? 2
          : (ws_size >= (size_t)48*1024*1024) ? 1 : 0;
  const int SK = (cfg >= 1) ? 5 : 2;
  const int SPP = (94 + SK - 1) / SK;

  char* ws = (char*)d_ws;
  size_t off = 0;
  auto alloc = [&](size_t bytes)->char*{
    char* p = ws + off; off = (off + bytes + 255) & ~(size_t)255; return p;
  };
  int*  flag  = (int*) alloc(256);
  u16*  x_bf  = (u16*) alloc((size_t)PLANE*2);
  u16*  h0_bf = (u16*) alloc((size_t)PLANE*2);
  u16*  hT    = (u16*) alloc((size_t)PLANE*2);
  u16*  a_p   = (u16*) alloc((size_t)2048*320*2);
  u16*  v_p   = (u16*) alloc((size_t)2048*384*2);
  u16* WaT = (u16*)alloc(224*320*2);
  u16* WvT = (u16*)alloc(224*384*2);
  u16* WlT = (u16*)alloc(224*1024*2);
  u16* W0T = (u16*)alloc(224*256*2);
  u16* WtT = (u16*)alloc((size_t)8*224*256*2);
  u16* WbT = (u16*)alloc((size_t)8*224*256*2);
  int* spk = (int*)alloc(2000*4);
  u16* spkem = (u16*)alloc(400*2);
  u16* b_all = (u16*)alloc(800*2);
  u16* part = (u16*)alloc((size_t)SK*PLANE*2);
  u16* adj_bf = (cfg == 2) ? (u16*)alloc((size_t)6016*6016*2) : nullptr;

  detect_kernel<<<1,64,0,stream>>>((const u16*)adj, flag);

  if (cfg == 2)
    conv_kernel<<<dim3(17672),256,0,stream>>>(flag, adj, adj_bf);

  prep_kernel<<<dim3(PB_END),256,0,stream>>>(flag,
      Wa,Wv,Wl,W0,convW,qmask, a,v,spk_emb, ba,bv,bl,b0,
      WaT,WvT,WlT,W0T,WtT,WbT, spk, x_bf, a_p,v_p, spkem, b_all);

  // modality projections -> x (rows 0/2000/4000)   [BM=32, 64 blocks]
  gemm_kernel<1><<<dim3(64,1),256,0,stream>>>(0, nullptr, nullptr,
      a_p,320,320,320,5, WaT,320,
      2048,2000, 5, 1, b_all, nullptr, nullptr,
      nullptr, x_bf, nullptr);
  gemm_kernel<1><<<dim3(64,1),256,0,stream>>>(0, nullptr, nullptr,
      v_p,384,384,384,6, WvT,384,
      2048,2000, 6, 1, b_all+200, nullptr, nullptr,
      nullptr, x_bf + (size_t)2000*LDC, nullptr);
  // l read directly (lda=1024, 8-aligned); dtype via flag
  gemm_kernel<1><<<dim3(64,1),256,0,stream>>>(1, flag, nullptr,
      l,1024,1024,1024,16, WlT,1024,
      2000,2000, 16, 1, b_all+400, spkem, spk,
      nullptr, x_bf + (size_t)4000*LDC, nullptr);

  // h0 = relu(x@W0 + b0); also h = h0 (write hT)   [BM=32, 188 blocks]
  gemm_kernel<1><<<dim3(188,1),256,0,stream>>>(0, nullptr, nullptr,
      x_bf,LDC,LDC,256,4, W0T,256,
      NROWS,NROWS, 4, 2, b_all+600, nullptr, nullptr,
      nullptr, h0_bf, hT);

  for (int i=0;i<8;i++){
    float theta = logf(0.5f/(float)(i+1) + 1.0f);
    // hi = adj @ h   (split-K -> bf16 partials)   [BM=64]
    if (cfg == 2)
      gemm_kernel<2><<<dim3(94,SK),256,0,stream>>>(3, flag, adj_bf,
          adj,6000,6000,6000,94, hT,NROWS,
          6000,0, SPP, 0, nullptr, nullptr, nullptr,
          part, nullptr, nullptr);
    else
      gemm_kernel<2><<<dim3(94,SK),256,0,stream>>>(1, flag, nullptr,
          adj,6000,6000,6000,94, hT,NROWS,
          6000,0, SPP, 0, nullptr, nullptr, nullptr,
          part, nullptr, nullptr);
    // h = relu(theta*(hi@Wt + h0@Wb) + (1-theta)*(0.9 hi + 0.1 h0)) -> hT
    layer_kernel<<<dim3(188),256,0,stream>>>(part, SK, h0_bf,
        WtT + (size_t)i*57344, WbT + (size_t)i*57344, theta, hT);
  }

  out_kernel<<<dim3(32,3),256,0,stream>>>(flag, x_bf, hT, (void*)d_out);
}